// Round 3
// baseline (105.781 us; speedup 1.0000x reference)
//
#include <hip/hip_runtime.h>

// Problem dims (fixed by setup_inputs): S=256, BT=32, D=128, N=128, O=128
#define S_DIM 256
#define BT_DIM 32
#define D_DIM 128
#define N_DIM 128
#define O_DIM 128
#define SB (S_DIM * BT_DIM)   // 8192 flattened (s,b) rows

// Transpose both weight matrices (each 128x128): Wt[k][n] = W[n][k].
// Reads strided (L2-resident, 64 KB each), writes coalesced.
__global__ __launch_bounds__(256) void transpose2(const float* __restrict__ B,
                                                  const float* __restrict__ C,
                                                  float* __restrict__ Bt,
                                                  float* __restrict__ Ct) {
    int id = blockIdx.x * 256 + threadIdx.x;   // 0..32767
    const float* src = B;
    float* dst = Bt;
    if (id >= 16384) { src = C; dst = Ct; id -= 16384; }
    const int k = id >> 7, n = id & 127;
    dst[k * 128 + n] = src[n * 128 + k];
}

// out[r][n] = sum_k A[r][k] * W[n][k], given Wt[k][n] (= W transposed).
// One wave per block. Wave computes 8 rows x all 128 cols.
// Lane l owns cols {2l, 2l+1}; W-slab (32 k's) held in 64 VGPRs, loaded
// COALESCED from Wt. A row values: indices depend only on blockIdx/loop
// constants -> wave-uniform -> compiler emits s_load (scalar pipe, no LDS,
// no vector-memory traffic). FMA reads the A value from an SGPR operand.
__global__ __launch_bounds__(64) void gemm_ws(const float* __restrict__ A,
                                              const float* __restrict__ Wt,
                                              float* __restrict__ out) {
    const int l = threadIdx.x;       // 0..63
    const int r0 = blockIdx.x * 8;   // 8 rows per wave

    float acc[8][2];
    #pragma unroll
    for (int r = 0; r < 8; ++r) { acc[r][0] = 0.f; acc[r][1] = 0.f; }

    for (int s = 0; s < 4; ++s) {    // K in 4 slabs of 32
        const int k0 = s * 32;

        float2 wf[32];               // static indices only -> stays in VGPRs
        #pragma unroll
        for (int k = 0; k < 32; ++k)
            wf[k] = *reinterpret_cast<const float2*>(&Wt[(size_t)(k0 + k) * N_DIM + 2 * l]);

        #pragma unroll
        for (int r = 0; r < 8; ++r) {
            const float* __restrict__ Arow = A + (size_t)(r0 + r) * D_DIM + k0;
            #pragma unroll
            for (int k = 0; k < 32; ++k) {
                const float a = Arow[k];             // uniform -> s_load
                acc[r][0] = fmaf(a, wf[k].x, acc[r][0]);
                acc[r][1] = fmaf(a, wf[k].y, acc[r][1]);
            }
        }
    }

    #pragma unroll
    for (int r = 0; r < 8; ++r)
        *reinterpret_cast<float2*>(&out[(size_t)(r0 + r) * N_DIM + 2 * l]) =
            make_float2(acc[r][0], acc[r][1]);
}

// Per-(b,n) linear scan over time: h_t = lam*h_{t-1} + gamma*Bx_t.
// 4096 chains; 64 blocks x 64 threads spread across 64 CUs.
// Also writes hT (final h) to the d_out tail.
__global__ __launch_bounds__(64) void scan_kernel(const float* __restrict__ Bx,
                                                  const float* __restrict__ lambda_log,
                                                  float* __restrict__ hs,
                                                  float* __restrict__ hT) {
    const int idx = blockIdx.x * 64 + threadIdx.x;  // (b,n): b=idx/128, n=idx%128
    const int n = idx & 127;

    const float ll    = lambda_log[n];
    const float lam   = expf(-expf(ll));
    const float gamma = sqrtf(1.0f - lam * lam + 1e-7f);

    float h = 0.0f;
    const int stride = BT_DIM * N_DIM;  // 4096
    for (int t0 = 0; t0 < S_DIM; t0 += 8) {
        float bx[8];
        #pragma unroll
        for (int k = 0; k < 8; ++k)
            bx[k] = Bx[(size_t)(t0 + k) * stride + idx];   // 8 loads in flight
        #pragma unroll
        for (int k = 0; k < 8; ++k) {
            h = fmaf(lam, h, gamma * bx[k]);
            hs[(size_t)(t0 + k) * stride + idx] = h;
        }
    }
    hT[idx] = h;
}

extern "C" void kernel_launch(void* const* d_in, const int* in_sizes, int n_in,
                              void* d_out, int out_size, void* d_ws, size_t ws_size,
                              hipStream_t stream) {
    const float* x          = (const float*)d_in[0];  // [S][BT][D]
    const float* lambda_log = (const float*)d_in[1];  // [N]
    const float* B          = (const float*)d_in[2];  // [N][D]
    const float* C          = (const float*)d_in[3];  // [O][N]

    float* out = (float*)d_out;                  // outputs [S][BT][O] then hT [BT][N]
    float* Bx  = (float*)d_ws;                   // [SB][N]  4 MB
    float* hs  = Bx + (size_t)SB * N_DIM;        // [SB][N]  4 MB
    float* Bt  = hs + (size_t)SB * N_DIM;        // [D][N]   64 KB
    float* Ct  = Bt + D_DIM * N_DIM;             // [N][O]   64 KB

    // 0) transpose B and C (weights) for coalesced W-fragment loads
    transpose2<<<128, 256, 0, stream>>>(B, C, Bt, Ct);

    // 1) Bx = X @ B^T
    gemm_ws<<<SB / 8, 64, 0, stream>>>(x, Bt, Bx);

    // 2) time scan per (b,n); writes hs and hT
    scan_kernel<<<(BT_DIM * N_DIM) / 64, 64, 0, stream>>>(
        Bx, lambda_log, hs, out + (size_t)SB * O_DIM);

    // 3) outputs = hs @ C^T
    gemm_ws<<<SB / 8, 64, 0, stream>>>(hs, Ct, out);
}

// Round 5
// 93.442 us; speedup vs baseline: 1.1320x; 1.1320x over previous
//
#include <hip/hip_runtime.h>

// Problem dims (fixed by setup_inputs): S=256, BT=32, D=128, N=128, O=128
#define S_DIM 256
#define BT_DIM 32
#define D_DIM 128
#define N_DIM 128
#define O_DIM 128
#define SB (S_DIM * BT_DIM)   // 8192 flattened (s,b) rows
#define NT 16                 // n-tile (K1) / o-tile (K2) per block
#define EPS 1e-7f

// ---------------------------------------------------------------------------
// K1: fused  Bx = X @ B^T  ->  time-scan  ->  hsT (transposed) + hT.
// Block = (b, nt): 32*8 = 256 blocks, 512 threads (t = jh*256 + s).
// GEMM: thread s loads X[s,b,:] in 64B chunks to regs; B-tile in LDS, all
// reads wave-uniform -> broadcast (no conflicts). 8 accumulators/thread.
// Scan: two-level (16 chunks x 16 steps) in LDS; no cross-block dependency.
// hs written TRANSPOSED: hsT[n][s*BT+b] so K2 reads are coalesced.
// ---------------------------------------------------------------------------
__global__ __launch_bounds__(512) void k1_gemm_scan(const float* __restrict__ X,
                                                    const float* __restrict__ lamlog,
                                                    const float* __restrict__ B,
                                                    float* __restrict__ hsT,
                                                    float* __restrict__ hT) {
    __shared__ float Bs[NT][D_DIM];        // 8 KB  (broadcast reads; no pad needed)
    __shared__ float Bxs[S_DIM][NT + 1];   // ~17 KB (pad: 17 dwords/row, odd -> conflict-free)
    __shared__ float carr[16][NT + 1];     // ~1 KB

    const int b  = blockIdx.x >> 3;        // 0..31
    const int nt = blockIdx.x & 7;         // 0..7
    const int n0 = nt * NT;
    const int t  = threadIdx.x;
    const int s  = t & 255;
    const int jh = t >> 8;                 // 0/1 -> j half
    const int j0 = jh * 8;

    // Stage B tile: 16x128 fp32 = 512 float4; one per thread, coalesced.
    reinterpret_cast<float4*>(&Bs[0][0])[t] =
        reinterpret_cast<const float4*>(B + (size_t)n0 * D_DIM)[t];
    __syncthreads();

    // GEMM: bx[j] = X[s,b,:] . B[n0+j0+j,:]
    const float* __restrict__ xrow = X + (size_t)s * (BT_DIM * D_DIM) + b * D_DIM;
    float acc[8];
    #pragma unroll
    for (int j = 0; j < 8; ++j) acc[j] = 0.f;

    for (int dc = 0; dc < D_DIM; dc += 16) {   // 16 floats = one 64B line per lane
        float4 xv[4];
        #pragma unroll
        for (int q = 0; q < 4; ++q)
            xv[q] = *reinterpret_cast<const float4*>(xrow + dc + 4 * q);
        #pragma unroll
        for (int j = 0; j < 8; ++j) {
            #pragma unroll
            for (int q = 0; q < 4; ++q) {
                const float4 bv = *reinterpret_cast<const float4*>(&Bs[j0 + j][dc + 4 * q]);
                acc[j] = fmaf(xv[q].x, bv.x, acc[j]);
                acc[j] = fmaf(xv[q].y, bv.y, acc[j]);
                acc[j] = fmaf(xv[q].z, bv.z, acc[j]);
                acc[j] = fmaf(xv[q].w, bv.w, acc[j]);
            }
        }
    }

    #pragma unroll
    for (int j = 0; j < 8; ++j) Bxs[s][j0 + j] = acc[j];
    __syncthreads();

    // Two-level scan. Tasks: t<256 -> (j = t&15, c = t>>4); chunk c = s in [16c,16c+16).
    const int j = t & 15;
    const int c = (t >> 4) & 15;
    float lam = 0.f, gamma = 0.f, lam16 = 0.f;
    if (t < 256) {
        const float ll = lamlog[n0 + j];
        lam   = expf(-expf(ll));
        gamma = sqrtf(1.f - lam * lam + EPS);
        const float l2 = lam * lam, l4 = l2 * l2, l8 = l4 * l4;
        lam16 = l8 * l8;
        // pass 1: chunk carry (h through 16 steps from 0)
        float h = 0.f;
        #pragma unroll
        for (int i = 0; i < 16; ++i)
            h = fmaf(lam, h, gamma * Bxs[c * 16 + i][j]);
        carr[c][j] = h;
    }
    __syncthreads();
    if (t < 256) {
        // H entering chunk c: H(c) = lam16*H(c-1) + carr[c-1], H(0)=0
        float Hb = 0.f;
        for (int cp = 0; cp < c; ++cp)
            Hb = fmaf(lam16, Hb, carr[cp][j]);
        // pass 2: rescan chunk from Hb, write final h
        float h = Hb;
        float* __restrict__ dst = hsT + (size_t)(n0 + j) * SB + b;
        #pragma unroll
        for (int i = 0; i < 16; ++i) {
            h = fmaf(lam, h, gamma * Bxs[c * 16 + i][j]);
            dst[(size_t)(c * 16 + i) * BT_DIM] = h;
        }
        if (c == 15) hT[b * N_DIM + n0 + j] = h;   // final state
    }
}

// ---------------------------------------------------------------------------
// K2: out[r][o] = sum_n hsT[n][r] * C[o][n].
// Block = (rc, ot): 32*8 = 256 blocks, 512 threads (t = oh*256 + rl).
// hsT reads are lane-contiguous dwords (coalesced); C-tile in LDS broadcast.
// ---------------------------------------------------------------------------
__global__ __launch_bounds__(512) void k2_outgemm(const float* __restrict__ hsT,
                                                  const float* __restrict__ C,
                                                  float* __restrict__ out) {
    __shared__ float Cs[NT][N_DIM];   // 8 KB (broadcast reads)

    const int rc = blockIdx.x >> 3;   // 0..31 row-chunk (256 rows)
    const int ot = blockIdx.x & 7;    // 0..7
    const int o0 = ot * NT;
    const int t  = threadIdx.x;
    const int rl = t & 255;
    const int oh = t >> 8;
    const int j0 = oh * 8;
    const int r  = rc * 256 + rl;

    reinterpret_cast<float4*>(&Cs[0][0])[t] =
        reinterpret_cast<const float4*>(C + (size_t)o0 * N_DIM)[t];
    __syncthreads();

    float acc[8];
    #pragma unroll
    for (int j = 0; j < 8; ++j) acc[j] = 0.f;

    for (int nc = 0; nc < N_DIM; nc += 16) {
        float hv[16];
        #pragma unroll
        for (int q = 0; q < 16; ++q)
            hv[q] = hsT[(size_t)(nc + q) * SB + r];   // coalesced
        #pragma unroll
        for (int jj = 0; jj < 8; ++jj) {
            #pragma unroll
            for (int q4 = 0; q4 < 4; ++q4) {
                const float4 cv = *reinterpret_cast<const float4*>(&Cs[j0 + jj][nc + 4 * q4]);
                acc[jj] = fmaf(hv[4 * q4 + 0], cv.x, acc[jj]);
                acc[jj] = fmaf(hv[4 * q4 + 1], cv.y, acc[jj]);
                acc[jj] = fmaf(hv[4 * q4 + 2], cv.z, acc[jj]);
                acc[jj] = fmaf(hv[4 * q4 + 3], cv.w, acc[jj]);
            }
        }
    }

    float* __restrict__ orow = out + (size_t)r * O_DIM + o0 + j0;
    *reinterpret_cast<float4*>(orow)     = make_float4(acc[0], acc[1], acc[2], acc[3]);
    *reinterpret_cast<float4*>(orow + 4) = make_float4(acc[4], acc[5], acc[6], acc[7]);
}

extern "C" void kernel_launch(void* const* d_in, const int* in_sizes, int n_in,
                              void* d_out, int out_size, void* d_ws, size_t ws_size,
                              hipStream_t stream) {
    const float* x          = (const float*)d_in[0];  // [S][BT][D]
    const float* lambda_log = (const float*)d_in[1];  // [N]
    const float* B          = (const float*)d_in[2];  // [N][D]
    const float* C          = (const float*)d_in[3];  // [O][N]

    float* out = (float*)d_out;             // outputs [S][BT][O] then hT [BT][N]
    float* hT  = out + (size_t)SB * O_DIM;
    float* hsT = (float*)d_ws;              // [N][SB] transposed h states, 4 MB

    // K1: fused first GEMM + time scan (per-(b,n-tile) blocks, no cross-block dep)
    k1_gemm_scan<<<256, 512, 0, stream>>>(x, lambda_log, B, hsT, hT);

    // K2: outputs = hs @ C^T
    k2_outgemm<<<256, 512, 0, stream>>>(hsT, C, out);
}

// Round 6
// 75.292 us; speedup vs baseline: 1.4049x; 1.2411x over previous
//
#include <hip/hip_runtime.h>

// Problem dims (fixed): S=256, BT=32, D=128, N=128, O=128
#define S_DIM 256
#define BT_DIM 32
#define D_DIM 128
#define N_DIM 128
#define O_DIM 128
#define SB (S_DIM * BT_DIM)   // 8192 flattened (s,b) rows
#define EPS 1e-7f

typedef short s16x8 __attribute__((ext_vector_type(8)));  // 8 bf16 (4 VGPRs)
typedef float fx4   __attribute__((ext_vector_type(4)));

union U8 { unsigned short u[8]; s16x8 v; };

__device__ __forceinline__ unsigned short f2bf(float f) {
    unsigned u = __builtin_bit_cast(unsigned, f);
    return (unsigned short)((u + 0x7fffu + ((u >> 16) & 1u)) >> 16);  // RNE
}
__device__ __forceinline__ float bf2f(unsigned short h) {
    unsigned u = ((unsigned)h) << 16;
    return __builtin_bit_cast(float, u);
}
// split 8 fp32 -> bf16 hi + bf16 lo fragments
__device__ __forceinline__ void cvt8(const float4 f0, const float4 f1, s16x8& hi, s16x8& lo) {
    float f[8] = {f0.x, f0.y, f0.z, f0.w, f1.x, f1.y, f1.z, f1.w};
    U8 h, l;
    #pragma unroll
    for (int i = 0; i < 8; ++i) {
        unsigned short hb = f2bf(f[i]);
        h.u[i] = hb;
        l.u[i] = f2bf(f[i] - bf2f(hb));
    }
    hi = h.v; lo = l.v;
}
__device__ __forceinline__ void pack4(const float4 f, unsigned* hi2, unsigned* lo2) {
    float f_[4] = {f.x, f.y, f.z, f.w};
    unsigned short hb[4], lb[4];
    #pragma unroll
    for (int i = 0; i < 4; ++i) {
        hb[i] = f2bf(f_[i]);
        lb[i] = f2bf(f_[i] - bf2f(hb[i]));
    }
    hi2[0] = (unsigned)hb[0] | ((unsigned)hb[1] << 16);
    hi2[1] = (unsigned)hb[2] | ((unsigned)hb[3] << 16);
    lo2[0] = (unsigned)lb[0] | ((unsigned)lb[1] << 16);
    lo2[1] = (unsigned)lb[2] | ((unsigned)lb[3] << 16);
}

// ---------------------------------------------------------------------------
// K1: Bx = X @ B^T via split-bf16 MFMA, then two-level time scan.
// Grid 256 = (b 32) x (nt 8); block 256 thr = 4 waves.
// Wave w: 4 s-tiles of 16 s each (s0 = (4w+q)*16). M-dim of each MFMA tile =
// 16 s-values at fixed b; N-dim = 16 n. K=128 -> 4 k-slices, 3 MFMA each
// (hi*hi + hi*lo + lo*hi). hs stored as bf16 hi/lo row-major [r][n] for K2.
// ---------------------------------------------------------------------------
__global__ __launch_bounds__(256) void k1_gemm_scan(const float* __restrict__ X,
                                                    const float* __restrict__ lamlog,
                                                    const float* __restrict__ Bm,
                                                    unsigned short* __restrict__ hs_hi,
                                                    unsigned short* __restrict__ hs_lo,
                                                    float* __restrict__ hT) {
    __shared__ unsigned short Bhi[16][136];   // pad: 272B row stride -> conflict-light
    __shared__ unsigned short Blo[16][136];
    __shared__ float Bxs[S_DIM][17];
    __shared__ float carr[16][17];

    const int t  = threadIdx.x;
    const int b  = blockIdx.x >> 3;
    const int n0 = (blockIdx.x & 7) * 16;

    // Stage + convert B tile (rows n0..n0+15): 512 float4, 2 per thread, coalesced.
    #pragma unroll
    for (int q = 0; q < 2; ++q) {
        const int id4 = t + 256 * q;          // 0..511
        const int row = id4 >> 5, c4 = id4 & 31;
        const float4 f = *reinterpret_cast<const float4*>(Bm + (size_t)(n0 + row) * D_DIM + c4 * 4);
        unsigned hi2[2], lo2[2];
        pack4(f, hi2, lo2);
        *reinterpret_cast<uint2*>(&Bhi[row][c4 * 4]) = make_uint2(hi2[0], hi2[1]);
        *reinterpret_cast<uint2*>(&Blo[row][c4 * 4]) = make_uint2(lo2[0], lo2[1]);
    }
    __syncthreads();

    const int w  = t >> 6, l = t & 63;
    const int lr = l & 15;            // frag row (M or N index)
    const int lk = (l >> 4) * 8;      // frag k-offset base

    // B-fragments: load once per wave, reused for all s-tiles.
    s16x8 bh[4], bl[4];
    #pragma unroll
    for (int sl = 0; sl < 4; ++sl) {
        bh[sl] = *reinterpret_cast<const s16x8*>(&Bhi[lr][sl * 32 + lk]);
        bl[sl] = *reinterpret_cast<const s16x8*>(&Blo[lr][sl * 32 + lk]);
    }

    const float* __restrict__ xb = X + (size_t)b * D_DIM;
    #pragma unroll
    for (int q = 0; q < 4; ++q) {
        const int s0 = (w * 4 + q) * 16;
        const float* __restrict__ xr = xb + (size_t)(s0 + lr) * (BT_DIM * D_DIM);
        s16x8 ah[4], al[4];
        #pragma unroll
        for (int sl = 0; sl < 4; ++sl) {
            const float4 f0 = *reinterpret_cast<const float4*>(xr + sl * 32 + lk);
            const float4 f1 = *reinterpret_cast<const float4*>(xr + sl * 32 + lk + 4);
            cvt8(f0, f1, ah[sl], al[sl]);
        }
        fx4 acc = {0.f, 0.f, 0.f, 0.f};
        #pragma unroll
        for (int sl = 0; sl < 4; ++sl) {
            acc = __builtin_amdgcn_mfma_f32_16x16x32_bf16(ah[sl], bh[sl], acc, 0, 0, 0);
            acc = __builtin_amdgcn_mfma_f32_16x16x32_bf16(ah[sl], bl[sl], acc, 0, 0, 0);
            acc = __builtin_amdgcn_mfma_f32_16x16x32_bf16(al[sl], bh[sl], acc, 0, 0, 0);
        }
        // D: m=(l>>4)*4+r (s within tile), col=l&15 (n within tile)
        #pragma unroll
        for (int r = 0; r < 4; ++r)
            Bxs[s0 + (l >> 4) * 4 + r][lr] = acc[r];
    }
    __syncthreads();

    // Two-level scan (proven R5 structure): 256 tasks (j = n, c = chunk).
    const int j = t & 15;
    const int c = t >> 4;
    const float ll    = lamlog[n0 + j];
    const float lam   = expf(-expf(ll));
    const float gamma = sqrtf(1.f - lam * lam + EPS);
    const float l2 = lam * lam, l4 = l2 * l2, l8 = l4 * l4;
    const float lam16 = l8 * l8;

    float h = 0.f;
    #pragma unroll
    for (int i = 0; i < 16; ++i)
        h = fmaf(lam, h, gamma * Bxs[c * 16 + i][j]);
    carr[c][j] = h;
    __syncthreads();

    float Hb = 0.f;
    for (int cp = 0; cp < c; ++cp)
        Hb = fmaf(lam16, Hb, carr[cp][j]);

    h = Hb;
    #pragma unroll
    for (int i = 0; i < 16; ++i) {
        h = fmaf(lam, h, gamma * Bxs[c * 16 + i][j]);
        const size_t rg = (size_t)(c * 16 + i) * BT_DIM + b;     // global row
        const unsigned short hb = f2bf(h);
        hs_hi[rg * N_DIM + n0 + j] = hb;
        hs_lo[rg * N_DIM + n0 + j] = f2bf(h - bf2f(hb));
    }
    if (c == 15) hT[b * N_DIM + n0 + j] = h;
}

// ---------------------------------------------------------------------------
// K2: out = hs @ C^T via split-bf16 MFMA.
// Grid 256 blocks x 256 thr (4 waves); block = 32 rows x 128 o.
// C converted once per block into LDS (bf16 hi/lo, padded rows).
// Wave w: rows r0+16*(w&1), o-tiles (w>>1)*4 .. +3.
// ---------------------------------------------------------------------------
__global__ __launch_bounds__(256) void k2_outgemm(const unsigned short* __restrict__ hs_hi,
                                                  const unsigned short* __restrict__ hs_lo,
                                                  const float* __restrict__ Cm,
                                                  float* __restrict__ out) {
    __shared__ unsigned short Chi[128][136];  // 34 KB
    __shared__ unsigned short Clo[128][136];  // 34 KB

    const int t  = threadIdx.x;
    const int r0 = blockIdx.x * 32;

    // Stage + convert all of C: 4096 float4, 16 per thread, coalesced.
    #pragma unroll
    for (int q = 0; q < 16; ++q) {
        const int id4 = t + 256 * q;          // 0..4095
        const int row = id4 >> 5, c4 = id4 & 31;
        const float4 f = *reinterpret_cast<const float4*>(Cm + (size_t)row * N_DIM + c4 * 4);
        unsigned hi2[2], lo2[2];
        pack4(f, hi2, lo2);
        *reinterpret_cast<uint2*>(&Chi[row][c4 * 4]) = make_uint2(hi2[0], hi2[1]);
        *reinterpret_cast<uint2*>(&Clo[row][c4 * 4]) = make_uint2(lo2[0], lo2[1]);
    }
    __syncthreads();

    const int w  = t >> 6, l = t & 63;
    const int lr = l & 15;
    const int lk = (l >> 4) * 8;
    const int rbase = r0 + 16 * (w & 1) + lr;

    // A-fragments from hs (bf16 hi/lo, row-major): contiguous 16 B per lane.
    s16x8 ah[4], al[4];
    #pragma unroll
    for (int sl = 0; sl < 4; ++sl) {
        ah[sl] = *reinterpret_cast<const s16x8*>(&hs_hi[(size_t)rbase * N_DIM + sl * 32 + lk]);
        al[sl] = *reinterpret_cast<const s16x8*>(&hs_lo[(size_t)rbase * N_DIM + sl * 32 + lk]);
    }

    #pragma unroll
    for (int q = 0; q < 4; ++q) {
        const int o0 = (w >> 1) * 64 + q * 16;
        fx4 acc = {0.f, 0.f, 0.f, 0.f};
        #pragma unroll
        for (int sl = 0; sl < 4; ++sl) {
            const s16x8 bh = *reinterpret_cast<const s16x8*>(&Chi[o0 + lr][sl * 32 + lk]);
            const s16x8 bl = *reinterpret_cast<const s16x8*>(&Clo[o0 + lr][sl * 32 + lk]);
            acc = __builtin_amdgcn_mfma_f32_16x16x32_bf16(ah[sl], bh, acc, 0, 0, 0);
            acc = __builtin_amdgcn_mfma_f32_16x16x32_bf16(ah[sl], bl, acc, 0, 0, 0);
            acc = __builtin_amdgcn_mfma_f32_16x16x32_bf16(al[sl], bh, acc, 0, 0, 0);
        }
        const int rw = r0 + 16 * (w & 1) + (l >> 4) * 4;
        #pragma unroll
        for (int r = 0; r < 4; ++r)
            out[(size_t)(rw + r) * O_DIM + o0 + lr] = acc[r];
    }
}

extern "C" void kernel_launch(void* const* d_in, const int* in_sizes, int n_in,
                              void* d_out, int out_size, void* d_ws, size_t ws_size,
                              hipStream_t stream) {
    const float* x          = (const float*)d_in[0];  // [S][BT][D]
    const float* lambda_log = (const float*)d_in[1];  // [N]
    const float* B          = (const float*)d_in[2];  // [N][D]
    const float* C          = (const float*)d_in[3];  // [O][N]

    float* out = (float*)d_out;                       // [S][BT][O] then hT [BT][N]
    float* hT  = out + (size_t)SB * O_DIM;

    unsigned short* hs_hi = (unsigned short*)d_ws;            // [SB][N] bf16, 2 MB
    unsigned short* hs_lo = hs_hi + (size_t)SB * N_DIM;       // [SB][N] bf16, 2 MB

    k1_gemm_scan<<<256, 256, 0, stream>>>(x, lambda_log, B, hs_hi, hs_lo, hT);
    k2_outgemm<<<256, 256, 0, stream>>>(hs_hi, hs_lo, C, out);
}

// Round 7
// 73.907 us; speedup vs baseline: 1.4313x; 1.0187x over previous
//
#include <hip/hip_runtime.h>

// Problem dims (fixed): S=256, BT=32, D=128, N=128, O=128
#define S_DIM 256
#define BT_DIM 32
#define D_DIM 128
#define N_DIM 128
#define O_DIM 128
#define SB (S_DIM * BT_DIM)   // 8192 flattened (s,b) rows
#define EPS 1e-7f

typedef short s16x8 __attribute__((ext_vector_type(8)));  // 8 bf16 (4 VGPRs)
typedef float fx4   __attribute__((ext_vector_type(4)));

union U8 { unsigned short u[8]; s16x8 v; };

__device__ __forceinline__ unsigned short f2bf(float f) {
    unsigned u = __builtin_bit_cast(unsigned, f);
    return (unsigned short)((u + 0x7fffu + ((u >> 16) & 1u)) >> 16);  // RNE
}
__device__ __forceinline__ float bf2f(unsigned short h) {
    unsigned u = ((unsigned)h) << 16;
    return __builtin_bit_cast(float, u);
}
// 8 fp32 -> bf16 (hi only)
__device__ __forceinline__ s16x8 cvt8hi(const float4 f0, const float4 f1) {
    float f[8] = {f0.x, f0.y, f0.z, f0.w, f1.x, f1.y, f1.z, f1.w};
    U8 h;
    #pragma unroll
    for (int i = 0; i < 8; ++i) h.u[i] = f2bf(f[i]);
    return h.v;
}
// 4 fp32 -> bf16 hi + lo packed pairs
__device__ __forceinline__ void pack4(const float4 f, unsigned* hi2, unsigned* lo2) {
    float f_[4] = {f.x, f.y, f.z, f.w};
    unsigned short hb[4], lb[4];
    #pragma unroll
    for (int i = 0; i < 4; ++i) {
        hb[i] = f2bf(f_[i]);
        lb[i] = f2bf(f_[i] - bf2f(hb[i]));
    }
    hi2[0] = (unsigned)hb[0] | ((unsigned)hb[1] << 16);
    hi2[1] = (unsigned)hb[2] | ((unsigned)hb[3] << 16);
    lo2[0] = (unsigned)lb[0] | ((unsigned)lb[1] << 16);
    lo2[1] = (unsigned)lb[2] | ((unsigned)lb[3] << 16);
}

// ---------------------------------------------------------------------------
// K1: Bx = X @ B^T (split-bf16 MFMA: Xhi*Bhi + Xhi*Blo) -> two-level scan.
// Blocks 0..255: (b 32) x (nt 8), 256 thr = 4 waves; wave w owns 4 s-tiles.
// Blocks 256..263: one-time C -> bf16 hi/lo conversion into ws (for K2).
// hs stored bf16 (hi only) row-major [r][n].
// ---------------------------------------------------------------------------
__global__ __launch_bounds__(256) void k1_gemm_scan(const float* __restrict__ X,
                                                    const float* __restrict__ lamlog,
                                                    const float* __restrict__ Bm,
                                                    const float* __restrict__ Cm,
                                                    unsigned short* __restrict__ hs_hi,
                                                    unsigned short* __restrict__ Chi,
                                                    unsigned short* __restrict__ Clo,
                                                    float* __restrict__ hT) {
    const int t = threadIdx.x;

    if (blockIdx.x >= 256) {
        // C-convert: 8 blocks x 256 thr x 8 elems = 16384 = 128*128.
        const int id = (blockIdx.x - 256) * 256 + t;            // 0..2047
        const float4 f0 = reinterpret_cast<const float4*>(Cm)[id * 2];
        const float4 f1 = reinterpret_cast<const float4*>(Cm)[id * 2 + 1];
        unsigned h0[2], l0[2], h1[2], l1[2];
        pack4(f0, h0, l0);
        pack4(f1, h1, l1);
        *reinterpret_cast<uint4*>(Chi + (size_t)id * 8) = make_uint4(h0[0], h0[1], h1[0], h1[1]);
        *reinterpret_cast<uint4*>(Clo + (size_t)id * 8) = make_uint4(l0[0], l0[1], l1[0], l1[1]);
        return;
    }

    __shared__ unsigned short Bhi[16][136];
    __shared__ unsigned short Blo[16][136];
    __shared__ float Bxs[S_DIM][17];
    __shared__ float carr[16][17];

    const int b  = blockIdx.x >> 3;
    const int n0 = (blockIdx.x & 7) * 16;

    // Stage + convert B tile (rows n0..n0+15): 512 float4, 2/thread, coalesced.
    #pragma unroll
    for (int q = 0; q < 2; ++q) {
        const int id4 = t + 256 * q;
        const int row = id4 >> 5, c4 = id4 & 31;
        const float4 f = *reinterpret_cast<const float4*>(Bm + (size_t)(n0 + row) * D_DIM + c4 * 4);
        unsigned hi2[2], lo2[2];
        pack4(f, hi2, lo2);
        *reinterpret_cast<uint2*>(&Bhi[row][c4 * 4]) = make_uint2(hi2[0], hi2[1]);
        *reinterpret_cast<uint2*>(&Blo[row][c4 * 4]) = make_uint2(lo2[0], lo2[1]);
    }
    __syncthreads();

    const int w  = t >> 6, l = t & 63;
    const int lr = l & 15;            // frag row
    const int lk = (l >> 4) * 8;      // frag k-offset base

    s16x8 bh[4], bl[4];
    #pragma unroll
    for (int sl = 0; sl < 4; ++sl) {
        bh[sl] = *reinterpret_cast<const s16x8*>(&Bhi[lr][sl * 32 + lk]);
        bl[sl] = *reinterpret_cast<const s16x8*>(&Blo[lr][sl * 32 + lk]);
    }

    const float* __restrict__ xb = X + (size_t)b * D_DIM;
    #pragma unroll
    for (int q = 0; q < 4; ++q) {
        const int s0 = (w * 4 + q) * 16;
        const float* __restrict__ xr = xb + (size_t)(s0 + lr) * (BT_DIM * D_DIM);
        s16x8 ah[4];
        #pragma unroll
        for (int sl = 0; sl < 4; ++sl) {
            const float4 f0 = *reinterpret_cast<const float4*>(xr + sl * 32 + lk);
            const float4 f1 = *reinterpret_cast<const float4*>(xr + sl * 32 + lk + 4);
            ah[sl] = cvt8hi(f0, f1);
        }
        fx4 acc = {0.f, 0.f, 0.f, 0.f};
        #pragma unroll
        for (int sl = 0; sl < 4; ++sl) {
            acc = __builtin_amdgcn_mfma_f32_16x16x32_bf16(ah[sl], bh[sl], acc, 0, 0, 0);
            acc = __builtin_amdgcn_mfma_f32_16x16x32_bf16(ah[sl], bl[sl], acc, 0, 0, 0);
        }
        #pragma unroll
        for (int r = 0; r < 4; ++r)
            Bxs[s0 + (l >> 4) * 4 + r][lr] = acc[r];
    }
    __syncthreads();

    // Two-level scan: 256 tasks (j = n-within-tile, c = 16-step chunk).
    const int j = t & 15;
    const int c = t >> 4;
    const float ll    = lamlog[n0 + j];
    const float lam   = expf(-expf(ll));
    const float gamma = sqrtf(1.f - lam * lam + EPS);
    const float l2 = lam * lam, l4 = l2 * l2, l8 = l4 * l4;
    const float lam16 = l8 * l8;

    float h = 0.f;
    #pragma unroll
    for (int i = 0; i < 16; ++i)
        h = fmaf(lam, h, gamma * Bxs[c * 16 + i][j]);
    carr[c][j] = h;
    __syncthreads();

    float Hb = 0.f;
    for (int cp = 0; cp < c; ++cp)
        Hb = fmaf(lam16, Hb, carr[cp][j]);

    h = Hb;
    #pragma unroll
    for (int i = 0; i < 16; ++i) {
        h = fmaf(lam, h, gamma * Bxs[c * 16 + i][j]);
        const size_t rg = (size_t)(c * 16 + i) * BT_DIM + b;     // global row
        hs_hi[rg * N_DIM + n0 + j] = f2bf(h);
    }
    if (c == 15) hT[b * N_DIM + n0 + j] = h;
}

// ---------------------------------------------------------------------------
// K2: out = hs @ C^T  (hs_hi * Chi + hs_hi * Clo), no LDS, no conversion.
// 256 blocks x 256 thr (4 waves); block = 32 rows x 128 o.
// All fragments loaded directly from global (hs_hi 2 MB, Chi/Clo 32 KB: L2).
// ---------------------------------------------------------------------------
__global__ __launch_bounds__(256) void k2_outgemm(const unsigned short* __restrict__ hs_hi,
                                                  const unsigned short* __restrict__ Chi,
                                                  const unsigned short* __restrict__ Clo,
                                                  float* __restrict__ out) {
    const int t  = threadIdx.x;
    const int r0 = blockIdx.x * 32;
    const int w  = t >> 6, l = t & 63;
    const int lr = l & 15;
    const int lk = (l >> 4) * 8;
    const int rbase = r0 + 16 * (w & 1) + lr;

    // A-fragments from hs_hi (row-major bf16): contiguous 16 B per lane.
    s16x8 ah[4];
    #pragma unroll
    for (int sl = 0; sl < 4; ++sl)
        ah[sl] = *reinterpret_cast<const s16x8*>(&hs_hi[(size_t)rbase * N_DIM + sl * 32 + lk]);

    #pragma unroll
    for (int q = 0; q < 4; ++q) {
        const int o0 = (w >> 1) * 64 + q * 16;
        fx4 acc = {0.f, 0.f, 0.f, 0.f};
        #pragma unroll
        for (int sl = 0; sl < 4; ++sl) {
            const s16x8 bh = *reinterpret_cast<const s16x8*>(&Chi[(size_t)(o0 + lr) * N_DIM + sl * 32 + lk]);
            const s16x8 bl = *reinterpret_cast<const s16x8*>(&Clo[(size_t)(o0 + lr) * N_DIM + sl * 32 + lk]);
            acc = __builtin_amdgcn_mfma_f32_16x16x32_bf16(ah[sl], bh, acc, 0, 0, 0);
            acc = __builtin_amdgcn_mfma_f32_16x16x32_bf16(ah[sl], bl, acc, 0, 0, 0);
        }
        const int rw = r0 + 16 * (w & 1) + (l >> 4) * 4;
        #pragma unroll
        for (int r = 0; r < 4; ++r)
            out[(size_t)(rw + r) * O_DIM + o0 + lr] = acc[r];
    }
}

extern "C" void kernel_launch(void* const* d_in, const int* in_sizes, int n_in,
                              void* d_out, int out_size, void* d_ws, size_t ws_size,
                              hipStream_t stream) {
    const float* x          = (const float*)d_in[0];  // [S][BT][D]
    const float* lambda_log = (const float*)d_in[1];  // [N]
    const float* B          = (const float*)d_in[2];  // [N][D]
    const float* C          = (const float*)d_in[3];  // [O][N]

    float* out = (float*)d_out;                       // [S][BT][O] then hT [BT][N]
    float* hT  = out + (size_t)SB * O_DIM;

    unsigned short* hs_hi = (unsigned short*)d_ws;            // [SB][N] bf16, 2 MB
    unsigned short* Chi   = hs_hi + (size_t)SB * N_DIM;       // [O][N] bf16, 32 KB
    unsigned short* Clo   = Chi + O_DIM * N_DIM;              // [O][N] bf16, 32 KB

    // K1 (+8 tail blocks pre-converting C for K2)
    k1_gemm_scan<<<264, 256, 0, stream>>>(x, lambda_log, B, C, hs_hi, Chi, Clo, hT);
    // K2
    k2_outgemm<<<256, 256, 0, stream>>>(hs_hi, Chi, Clo, out);
}